// Round 1
// baseline (1131.568 us; speedup 1.0000x reference)
//
#include <hip/hip_runtime.h>

#define N_NODES 50000
#define N_EDGES 800000
#define HDIM 128
#define NGRAPH 64
#define OUTDIM 10
#define NEG 0.1f
#define BN_EPS 1e-5f
#define PADN (64*782)   // 50048, N rounded up to 64

static __device__ __forceinline__ float leaky(float x){ return x >= 0.f ? x : NEG*x; }

__device__ __forceinline__ int lb(const int* a, int n, int v){
  int lo = 0, hi = n;
  while (lo < hi){ int m = (lo+hi)>>1; if (a[m] < v) lo = m+1; else hi = m; }
  return lo;
}

// ---------------- CSR build ----------------
__global__ __launch_bounds__(256) void hist_kernel(const int* __restrict__ dst, int* __restrict__ deg){
  int e = blockIdx.x*256 + threadIdx.x;
  if (e < N_EDGES) atomicAdd(&deg[dst[e]], 1);
}

__global__ __launch_bounds__(1024) void scan_kernel(const int* __restrict__ deg,
        int* __restrict__ offsets, int* __restrict__ cursor){
  __shared__ int sums[1024];
  const int tid = threadIdx.x;
  const int chunk = (N_NODES + 1023)/1024;
  const int base = tid*chunk;
  int s = 0;
  for (int i = 0; i < chunk; i++){ int idx = base+i; if (idx < N_NODES) s += deg[idx]; }
  sums[tid] = s; __syncthreads();
  for (int off = 1; off < 1024; off <<= 1){
    int v = 0;
    if (tid >= off) v = sums[tid-off];
    __syncthreads();
    if (tid >= off) sums[tid] += v;
    __syncthreads();
  }
  int run = sums[tid] - s;  // exclusive prefix of this thread's chunk
  for (int i = 0; i < chunk; i++){
    int idx = base+i;
    if (idx < N_NODES){ offsets[idx] = run; cursor[idx] = run; run += deg[idx]; }
  }
  if (tid == 1023) offsets[N_NODES] = sums[1023];
}

__global__ __launch_bounds__(256) void fill_kernel(const int* __restrict__ src, const int* __restrict__ dst,
        int* __restrict__ cursor, int* __restrict__ col){
  int e = blockIdx.x*256 + threadIdx.x;
  if (e < N_EDGES){
    int d = dst[e];
    int pos = atomicAdd(&cursor[d], 1);
    col[pos] = src[e];
  }
}

// ---------------- GIN aggregation: out[v] = h[v] + sum_{u in in(v)} h[u] ----------------
__global__ __launch_bounds__(256) void aggregate_kernel(const float* __restrict__ h,
        const int* __restrict__ offsets, const int* __restrict__ col,
        float* __restrict__ out){
  int v = (blockIdx.x*256 + threadIdx.x) >> 6;   // one wave per node
  int lane = threadIdx.x & 63;
  if (v >= N_NODES) return;
  int s = offsets[v], e = offsets[v+1];
  const float2* hp = (const float2*)h;
  float2 acc = hp[(size_t)v*64 + lane];          // self term (eps = 0)
  for (int j = s; j < e; j++){
    int u = col[j];                               // wave-uniform
    float2 t = hp[(size_t)u*64 + lane];
    acc.x += t.x; acc.y += t.y;
  }
  ((float2*)out)[(size_t)v*64 + lane] = acc;
}

// ---------------- GEMM (N x 128) @ (128 x 128) + bias, LeakyReLU fused ----------------
// block: 64 rows x 64 cols (blockIdx.y selects col half); 256 threads, 4x4 micro-tile
__global__ __launch_bounds__(256) void gemm_leaky_kernel(const float* __restrict__ A,
      const float* __restrict__ W, const float* __restrict__ bias,
      float* __restrict__ out, int nrows){
  __shared__ __align__(16) float As[64*132];   // +4 pad: kills same-bank column reads
  __shared__ __align__(16) float Ws[128*64];
  const int tid = threadIdx.x;
  const int row0 = blockIdx.x*64;
  const int co = blockIdx.y*64;

  {
    const float4* W4 = (const float4*)W;
    #pragma unroll
    for (int i = 0; i < 8; i++){
      int idx = tid + 256*i;                  // 2048 float4
      int k = idx >> 4, cq = idx & 15;
      *(float4*)&Ws[k*64 + cq*4] = W4[k*32 + blockIdx.y*16 + cq];
    }
  }
  {
    const float4* A4 = (const float4*)A;
    #pragma unroll
    for (int i = 0; i < 8; i++){
      int idx = tid + 256*i;                  // 2048 float4
      int r = idx >> 5, q = idx & 31;
      float4 v = make_float4(0.f, 0.f, 0.f, 0.f);
      if (row0 + r < nrows) v = A4[row0*32 + idx];
      *(float4*)&As[r*132 + q*4] = v;
    }
  }
  __syncthreads();

  const int tx = tid & 15, ty = tid >> 4;
  const int c0 = tx*4, r0 = ty*4;
  float acc[4][4];
  #pragma unroll
  for (int r = 0; r < 4; r++){
    #pragma unroll
    for (int c = 0; c < 4; c++) acc[r][c] = 0.f;
  }

  #pragma unroll 8
  for (int k = 0; k < 128; k++){
    float4 w = *(const float4*)&Ws[k*64 + c0];
    float av[4];
    av[0] = As[(r0+0)*132 + k];
    av[1] = As[(r0+1)*132 + k];
    av[2] = As[(r0+2)*132 + k];
    av[3] = As[(r0+3)*132 + k];
    #pragma unroll
    for (int r = 0; r < 4; r++){
      acc[r][0] += av[r]*w.x;
      acc[r][1] += av[r]*w.y;
      acc[r][2] += av[r]*w.z;
      acc[r][3] += av[r]*w.w;
    }
  }

  float4 bv = *(const float4*)&bias[co + c0];
  #pragma unroll
  for (int r = 0; r < 4; r++){
    int row = row0 + r0 + r;
    if (row < nrows){
      float4 o;
      o.x = leaky(acc[r][0] + bv.x);
      o.y = leaky(acc[r][1] + bv.y);
      o.z = leaky(acc[r][2] + bv.z);
      o.w = leaky(acc[r][3] + bv.w);
      *(float4*)&out[(size_t)row*128 + co + c0] = o;
    }
  }
}

// ---------------- BN stats: per-column sum & sumsq ----------------
__global__ __launch_bounds__(256) void stats_kernel(const float* __restrict__ h, float* __restrict__ stats){
  __shared__ float ls[256], lq[256];
  int c = threadIdx.x & 127;
  int half = threadIdx.x >> 7;
  float s = 0.f, q = 0.f;
  for (int r = blockIdx.x*2 + half; r < N_NODES; r += 1024){
    float v = h[(size_t)r*128 + c];
    s += v; q += v*v;
  }
  ls[threadIdx.x] = s; lq[threadIdx.x] = q;
  __syncthreads();
  if (half == 0){
    s += ls[threadIdx.x + 128]; q += lq[threadIdx.x + 128];
    atomicAdd(&stats[c], s);
    atomicAdd(&stats[128 + c], q);
  }
}

__global__ void finalize_kernel(const float* __restrict__ stats, const float* __restrict__ g,
      const float* __restrict__ b, float* __restrict__ ss){
  int c = threadIdx.x;  // 128 threads
  float mu  = stats[c] * (1.f/N_NODES);
  float var = stats[128 + c] * (1.f/N_NODES) - mu*mu;
  float sc = g[c] * rsqrtf(var + BN_EPS);
  ss[c] = sc;
  ss[128 + c] = b[c] - mu*sc;
}

__global__ __launch_bounds__(256) void normalize_kernel(float* __restrict__ h, const float* __restrict__ ss){
  const float4* ss4 = (const float4*)ss;
  const int total = N_NODES*32;               // float4 count
  for (int i = blockIdx.x*256 + threadIdx.x; i < total; i += gridDim.x*256){
    float4 v = ((const float4*)h)[i];
    int cq = i & 31;
    float4 sc = ss4[cq], sh = ss4[32 + cq];
    v.x = leaky(v.x*sc.x + sh.x);
    v.y = leaky(v.y*sc.y + sh.y);
    v.z = leaky(v.z*sc.z + sh.z);
    v.w = leaky(v.w*sc.w + sh.w);
    ((float4*)h)[i] = v;
  }
}

// ---------------- pooling ----------------
__global__ __launch_bounds__(128) void pool_kernel(const float* __restrict__ h,
      const int* __restrict__ batch, float* __restrict__ pooled){
  int g = blockIdx.x >> 3, part = blockIdx.x & 7;
  int s = lb(batch, N_NODES, g), e = lb(batch, N_NODES, g+1);
  int len = e - s;
  int a  = s + ((len*part) >> 3);
  int b2 = s + ((len*(part+1)) >> 3);
  int c = threadIdx.x;
  float acc = 0.f;
  for (int r = a; r < b2; r++) acc += h[(size_t)r*128 + c];
  atomicAdd(&pooled[g*128 + c], acc);
}

// ---------------- head: fc1 + BN(64 rows) + leaky + fc2 ----------------
__global__ __launch_bounds__(256) void head_kernel(const float* __restrict__ pooled,
      const int* __restrict__ batch,
      const float* __restrict__ fc1w, const float* __restrict__ fc1b,
      const float* __restrict__ g, const float* __restrict__ b,
      const float* __restrict__ fc2w, const float* __restrict__ fc2b,
      float* __restrict__ out){
  __shared__ float z1[64*128];
  __shared__ float inv[64];
  __shared__ float scale_s[128], shift_s[128];
  const int tid = threadIdx.x;
  if (tid < 64){
    int s = lb(batch, N_NODES, tid), e = lb(batch, N_NODES, tid+1);
    inv[tid] = 1.f / fmaxf((float)(e - s), 1.f);
  }
  __syncthreads();
  #pragma unroll
  for (int i = 0; i < 32; i++){
    int o = tid + 256*i;            // 8192 outputs
    int row = o >> 7, colc = o & 127;
    float acc = 0.f;
    for (int k = 0; k < 128; k++) acc += pooled[row*128 + k] * fc1w[k*128 + colc];
    z1[o] = acc*inv[row] + fc1b[colc];
  }
  __syncthreads();
  if (tid < 128){
    float s = 0.f, q = 0.f;
    for (int i = 0; i < 64; i++){ float v = z1[i*128 + tid]; s += v; q += v*v; }
    float mu = s*(1.f/64.f), var = q*(1.f/64.f) - mu*mu;
    float sc = g[tid] * rsqrtf(var + BN_EPS);
    scale_s[tid] = sc;
    shift_s[tid] = b[tid] - mu*sc;
  }
  __syncthreads();
  #pragma unroll
  for (int i = 0; i < 32; i++){
    int o = tid + 256*i;
    int colc = o & 127;
    float v = z1[o]*scale_s[colc] + shift_s[colc];
    z1[o] = leaky(v);
  }
  __syncthreads();
  for (int o = tid; o < NGRAPH*OUTDIM; o += 256){
    int row = o / OUTDIM, colc = o - row*OUTDIM;
    float acc = fc2b[colc];
    for (int k = 0; k < 128; k++) acc += z1[row*128 + k] * fc2w[k*OUTDIM + colc];
    out[o] = acc;
  }
}

extern "C" void kernel_launch(void* const* d_in, const int* in_sizes, int n_in,
                              void* d_out, int out_size, void* d_ws, size_t ws_size,
                              hipStream_t stream){
  (void)in_sizes; (void)n_in; (void)out_size; (void)ws_size;
  const float* x     = (const float*)d_in[0];
  const int*   ei    = (const int*)d_in[1];
  const int*   batch = (const int*)d_in[2];
  const float* cwA[4]; const float* cbA[4]; const float* cwB[4]; const float* cbB[4];
  const float* bng[4]; const float* bnb[4];
  for (int l = 0; l < 4; l++){
    cwA[l] = (const float*)d_in[3 + l*6 + 0];
    cbA[l] = (const float*)d_in[3 + l*6 + 1];
    cwB[l] = (const float*)d_in[3 + l*6 + 2];
    cbB[l] = (const float*)d_in[3 + l*6 + 3];
    bng[l] = (const float*)d_in[3 + l*6 + 4];
    bnb[l] = (const float*)d_in[3 + l*6 + 5];
  }
  const float* fc1w = (const float*)d_in[27];
  const float* fc1b = (const float*)d_in[28];
  const float* fcg  = (const float*)d_in[29];
  const float* fcb  = (const float*)d_in[30];
  const float* fc2w = (const float*)d_in[31];
  const float* fc2b = (const float*)d_in[32];

  char* p = (char*)d_ws;
  auto alloc = [&](size_t bytes)->char* {
    char* r = p; p += (bytes + 511) & ~(size_t)511; return r;
  };
  int* deg     = (int*)alloc((size_t)N_NODES*4);
  int* offsets = (int*)alloc((size_t)(N_NODES+1)*4);
  int* cursor  = (int*)alloc((size_t)N_NODES*4);
  int* csr     = (int*)alloc((size_t)N_EDGES*4);
  float* bufA  = (float*)alloc((size_t)PADN*128*4);
  float* bufB  = (float*)alloc((size_t)PADN*128*4);
  float* bufC  = (float*)alloc((size_t)PADN*128*4);
  float* stats = (float*)alloc((size_t)(4*256 + 256 + NGRAPH*128)*4);
  float* ss     = stats + 4*256;
  float* pooled = ss + 256;

  hipMemsetAsync(deg, 0, (size_t)N_NODES*4, stream);
  hipMemsetAsync(stats, 0, (size_t)(4*256 + 256 + NGRAPH*128)*4, stream);

  hist_kernel<<<(N_EDGES+255)/256, 256, 0, stream>>>(ei + N_EDGES, deg);
  scan_kernel<<<1, 1024, 0, stream>>>(deg, offsets, cursor);
  fill_kernel<<<(N_EDGES+255)/256, 256, 0, stream>>>(ei, ei + N_EDGES, cursor, csr);

  dim3 gg(PADN/64, 2);
  const float* hcur = x;
  for (int l = 0; l < 4; l++){
    aggregate_kernel<<<(N_NODES+3)/4, 256, 0, stream>>>(hcur, offsets, csr, bufB);
    gemm_leaky_kernel<<<gg, 256, 0, stream>>>(bufB, cwA[l], cbA[l], bufC, N_NODES);
    gemm_leaky_kernel<<<gg, 256, 0, stream>>>(bufC, cwB[l], cbB[l], bufA, N_NODES);
    stats_kernel<<<512, 256, 0, stream>>>(bufA, stats + l*256);
    finalize_kernel<<<1, 128, 0, stream>>>(stats + l*256, bng[l], bnb[l], ss);
    normalize_kernel<<<1024, 256, 0, stream>>>(bufA, ss);
    hcur = bufA;
  }

  pool_kernel<<<NGRAPH*8, 128, 0, stream>>>(bufA, batch, pooled);
  head_kernel<<<1, 256, 0, stream>>>(pooled, batch, fc1w, fc1b, fcg, fcb, fc2w, fc2b,
                                     (float*)d_out);
}

// Round 2
// 776.277 us; speedup vs baseline: 1.4577x; 1.4577x over previous
//
#include <hip/hip_runtime.h>

#define N_NODES 50000
#define N_EDGES 800000
#define HDIM 128
#define NGRAPH 64
#define OUTDIM 10
#define NEG 0.1f
#define BN_EPS 1e-5f
#define PADN (64*782)   // 50048, N rounded up to 64
#define SCAN_B 196      // ceil(N_NODES/256)

static __device__ __forceinline__ float leaky(float x){ return x >= 0.f ? x : NEG*x; }

__device__ __forceinline__ int lb(const int* a, int n, int v){
  int lo = 0, hi = n;
  while (lo < hi){ int m = (lo+hi)>>1; if (a[m] < v) lo = m+1; else hi = m; }
  return lo;
}

// ---------------- CSR build ----------------
__global__ __launch_bounds__(256) void hist_kernel(const int* __restrict__ dst, int* __restrict__ deg){
  int e = blockIdx.x*256 + threadIdx.x;
  if (e < N_EDGES) atomicAdd(&deg[dst[e]], 1);
}

__global__ __launch_bounds__(256) void blocksum_kernel(const int* __restrict__ deg, int* __restrict__ bsum){
  __shared__ int red[256];
  int i = blockIdx.x*256 + threadIdx.x;
  red[threadIdx.x] = (i < N_NODES) ? deg[i] : 0;
  __syncthreads();
  for (int off = 128; off > 0; off >>= 1){
    if (threadIdx.x < off) red[threadIdx.x] += red[threadIdx.x + off];
    __syncthreads();
  }
  if (threadIdx.x == 0) bsum[blockIdx.x] = red[0];
}

__global__ __launch_bounds__(256) void scan2_kernel(const int* __restrict__ deg, const int* __restrict__ bsum,
        int* __restrict__ offsets, int* __restrict__ cursor){
  __shared__ int pre[256];
  __shared__ int sc[256];
  const int b = blockIdx.x, t = threadIdx.x;
  pre[t] = (t < b) ? bsum[t] : 0;
  __syncthreads();
  for (int off = 128; off > 0; off >>= 1){
    if (t < off) pre[t] += pre[t + off];
    __syncthreads();
  }
  const int base = pre[0];
  const int i = b*256 + t;
  const int v = (i < N_NODES) ? deg[i] : 0;
  sc[t] = v; __syncthreads();
  for (int off = 1; off < 256; off <<= 1){
    int add = (t >= off) ? sc[t-off] : 0;
    __syncthreads();
    sc[t] += add;
    __syncthreads();
  }
  if (i < N_NODES){
    int off_ = base + sc[t] - v;   // exclusive prefix
    offsets[i] = off_; cursor[i] = off_;
  }
  if (b == SCAN_B-1 && t == 255) offsets[N_NODES] = base + sc[255];
}

__global__ __launch_bounds__(256) void fill_kernel(const int* __restrict__ src, const int* __restrict__ dst,
        int* __restrict__ cursor, int* __restrict__ col){
  int e = blockIdx.x*256 + threadIdx.x;
  if (e < N_EDGES){
    int d = dst[e];
    int pos = atomicAdd(&cursor[d], 1);
    col[pos] = src[e];
  }
}

// ---------------- GIN aggregation: out[v] = h[v] + sum_{u in in(v)} h[u] ----------------
__global__ __launch_bounds__(256) void aggregate_kernel(const float* __restrict__ h,
        const int* __restrict__ offsets, const int* __restrict__ col,
        float* __restrict__ out){
  int v = (blockIdx.x*256 + threadIdx.x) >> 6;   // one wave per node
  int lane = threadIdx.x & 63;
  if (v >= N_NODES) return;
  int s = offsets[v], e = offsets[v+1];
  const float2* hp = (const float2*)h;
  float2 acc = hp[(size_t)v*64 + lane];          // self term (eps = 0)
  int j = s;
  for (; j + 4 <= e; j += 4){                    // unrolled: 4 gathers in flight
    int u0 = col[j], u1 = col[j+1], u2 = col[j+2], u3 = col[j+3];
    float2 t0 = hp[(size_t)u0*64 + lane];
    float2 t1 = hp[(size_t)u1*64 + lane];
    float2 t2 = hp[(size_t)u2*64 + lane];
    float2 t3 = hp[(size_t)u3*64 + lane];
    acc.x += (t0.x + t1.x) + (t2.x + t3.x);
    acc.y += (t0.y + t1.y) + (t2.y + t3.y);
  }
  for (; j < e; j++){
    int u = col[j];
    float2 t = hp[(size_t)u*64 + lane];
    acc.x += t.x; acc.y += t.y;
  }
  ((float2*)out)[(size_t)v*64 + lane] = acc;
}

// ---------------- GEMM (N x 128) @ (128 x 128) + bias, LeakyReLU; optional fused BN stats --------
// block: 64 rows x 64 cols (blockIdx.y = col half); 256 threads, 4x4 micro-tile
template<bool STATS>
__global__ __launch_bounds__(256) void gemm_leaky_kernel(const float* __restrict__ A,
      const float* __restrict__ W, const float* __restrict__ bias,
      float* __restrict__ out, int nrows, float* __restrict__ stats){
  __shared__ __align__(16) float As[64*132];   // +4 pad
  __shared__ __align__(16) float Ws[128*64];
  const int tid = threadIdx.x;
  const int row0 = blockIdx.x*64;
  const int co = blockIdx.y*64;

  {
    const float4* W4 = (const float4*)W;
    #pragma unroll
    for (int i = 0; i < 8; i++){
      int idx = tid + 256*i;                  // 2048 float4
      int k = idx >> 4, cq = idx & 15;
      *(float4*)&Ws[k*64 + cq*4] = W4[k*32 + blockIdx.y*16 + cq];
    }
  }
  {
    const float4* A4 = (const float4*)A;
    #pragma unroll
    for (int i = 0; i < 8; i++){
      int idx = tid + 256*i;                  // 2048 float4
      int r = idx >> 5, q = idx & 31;
      float4 v = make_float4(0.f, 0.f, 0.f, 0.f);
      if (row0 + r < nrows) v = A4[row0*32 + idx];
      *(float4*)&As[r*132 + q*4] = v;
    }
  }
  __syncthreads();

  const int tx = tid & 15, ty = tid >> 4;
  const int c0 = tx*4, r0 = ty*4;
  float acc[4][4] = {};

  #pragma unroll 4
  for (int k0 = 0; k0 < 128; k0 += 4){
    float4 ar[4], wr[4];
    #pragma unroll
    for (int r = 0; r < 4; r++) ar[r] = *(const float4*)&As[(r0+r)*132 + k0];
    #pragma unroll
    for (int q = 0; q < 4; q++) wr[q] = *(const float4*)&Ws[(k0+q)*64 + c0];
    #pragma unroll
    for (int r = 0; r < 4; r++){
      #pragma unroll
      for (int q = 0; q < 4; q++){
        float av = (&ar[r].x)[q];
        acc[r][0] += av*wr[q].x;
        acc[r][1] += av*wr[q].y;
        acc[r][2] += av*wr[q].z;
        acc[r][3] += av*wr[q].w;
      }
    }
  }

  float4 bv = *(const float4*)&bias[co + c0];
  float sC[4] = {0,0,0,0}, qC[4] = {0,0,0,0};
  #pragma unroll
  for (int r = 0; r < 4; r++){
    int row = row0 + r0 + r;
    if (row < nrows){
      float4 o;
      o.x = leaky(acc[r][0] + bv.x);
      o.y = leaky(acc[r][1] + bv.y);
      o.z = leaky(acc[r][2] + bv.z);
      o.w = leaky(acc[r][3] + bv.w);
      *(float4*)&out[(size_t)row*128 + co + c0] = o;
      if (STATS){
        sC[0] += o.x; qC[0] += o.x*o.x;
        sC[1] += o.y; qC[1] += o.y*o.y;
        sC[2] += o.z; qC[2] += o.z*o.z;
        sC[3] += o.w; qC[3] += o.w*o.w;
      }
    }
  }

  if (STATS){
    __syncthreads();                           // As reads all done; reuse as scratch
    float* redS = As;                          // [64][17]
    float* redQ = As + 64*17;
    #pragma unroll
    for (int j2 = 0; j2 < 4; j2++){
      redS[(c0+j2)*17 + ty] = sC[j2];
      redQ[(c0+j2)*17 + ty] = qC[j2];
    }
    __syncthreads();
    if (tid < 64){
      float S = 0.f, Q = 0.f;
      #pragma unroll
      for (int t2 = 0; t2 < 16; t2++){ S += redS[tid*17 + t2]; Q += redQ[tid*17 + t2]; }
      atomicAdd(&stats[co + tid], S);
      atomicAdd(&stats[128 + co + tid], Q);
    }
  }
}

// ---------------- fused BN finalize + normalize + leaky ----------------
__global__ __launch_bounds__(256) void normalize_kernel(float* __restrict__ h,
      const float* __restrict__ stats, const float* __restrict__ g, const float* __restrict__ b){
  __shared__ float sc_s[128], sh_s[128];
  int t = threadIdx.x;
  if (t < 128){
    float mu  = stats[t] * (1.f/N_NODES);
    float var = stats[128 + t] * (1.f/N_NODES) - mu*mu;
    float s = g[t] * rsqrtf(var + BN_EPS);
    sc_s[t] = s;
    sh_s[t] = b[t] - mu*s;
  }
  __syncthreads();
  const int total = N_NODES*32;               // float4 count
  for (int i = blockIdx.x*256 + threadIdx.x; i < total; i += gridDim.x*256){
    float4 v = ((const float4*)h)[i];
    int c4 = (i & 31)*4;
    float4 sc = *(float4*)&sc_s[c4];
    float4 sh = *(float4*)&sh_s[c4];
    v.x = leaky(v.x*sc.x + sh.x);
    v.y = leaky(v.y*sc.y + sh.y);
    v.z = leaky(v.z*sc.z + sh.z);
    v.w = leaky(v.w*sc.w + sh.w);
    ((float4*)h)[i] = v;
  }
}

// ---------------- pooling with fused BN+leaky (layer 4) ----------------
__global__ __launch_bounds__(128) void pool_kernel(const float* __restrict__ h,
      const int* __restrict__ batch, const float* __restrict__ stats,
      const float* __restrict__ g, const float* __restrict__ b, float* __restrict__ pooled){
  int gi = blockIdx.x >> 3, part = blockIdx.x & 7;
  int c = threadIdx.x;
  float mu  = stats[c] * (1.f/N_NODES);
  float var = stats[128 + c] * (1.f/N_NODES) - mu*mu;
  float s = g[c] * rsqrtf(var + BN_EPS);
  float sh = b[c] - mu*s;
  int s0 = lb(batch, N_NODES, gi), e0 = lb(batch, N_NODES, gi+1);
  int len = e0 - s0;
  int a  = s0 + ((len*part) >> 3);
  int b2 = s0 + ((len*(part+1)) >> 3);
  float acc = 0.f;
  for (int r = a; r < b2; r++) acc += leaky(h[(size_t)r*128 + c]*s + sh);
  atomicAdd(&pooled[gi*128 + c], acc);
}

// ---------------- head: fc1 (parallel over graphs) ----------------
__global__ __launch_bounds__(128) void fc1_kernel(const float* __restrict__ pooled,
      const int* __restrict__ batch, const float* __restrict__ fc1w,
      const float* __restrict__ fc1b, float* __restrict__ z1){
  __shared__ float ps[128];
  __shared__ float invs;
  const int gi = blockIdx.x, t = threadIdx.x;
  if (t == 0){
    int s = lb(batch, N_NODES, gi), e = lb(batch, N_NODES, gi+1);
    invs = 1.f / fmaxf((float)(e - s), 1.f);
  }
  ps[t] = pooled[gi*128 + t];
  __syncthreads();
  float inv = invs;
  float acc = 0.f;
  #pragma unroll 8
  for (int k = 0; k < 128; k++) acc += ps[k]*fc1w[k*128 + t];   // coalesced, L2-hot
  z1[gi*128 + t] = acc*inv + fc1b[t];
}

// ---------------- head: BN(64 rows) + leaky + fc2 ----------------
__global__ __launch_bounds__(256) void head2_kernel(const float* __restrict__ z1,
      const float* __restrict__ g, const float* __restrict__ b,
      const float* __restrict__ fc2w, const float* __restrict__ fc2b,
      float* __restrict__ out){
  __shared__ float z[64*128];
  __shared__ float sc_s[128], sh_s[128];
  const int t = threadIdx.x;
  for (int i = t; i < 8192; i += 256) z[i] = z1[i];
  __syncthreads();
  if (t < 128){
    float s = 0.f, q = 0.f;
    for (int r = 0; r < 64; r++){ float v = z[r*128 + t]; s += v; q += v*v; }
    float mu = s*(1.f/64.f), var = q*(1.f/64.f) - mu*mu;
    float scv = g[t] * rsqrtf(var + BN_EPS);
    sc_s[t] = scv; sh_s[t] = b[t] - mu*scv;
  }
  __syncthreads();
  for (int i = t; i < 8192; i += 256){ int c = i & 127; z[i] = leaky(z[i]*sc_s[c] + sh_s[c]); }
  __syncthreads();
  for (int o = t; o < NGRAPH*OUTDIM; o += 256){
    int row = o/OUTDIM, c = o - row*OUTDIM;
    float acc = fc2b[c];
    for (int k = 0; k < 128; k++) acc += z[row*128 + k]*fc2w[k*OUTDIM + c];
    out[o] = acc;
  }
}

extern "C" void kernel_launch(void* const* d_in, const int* in_sizes, int n_in,
                              void* d_out, int out_size, void* d_ws, size_t ws_size,
                              hipStream_t stream){
  (void)in_sizes; (void)n_in; (void)out_size; (void)ws_size;
  const float* x     = (const float*)d_in[0];
  const int*   ei    = (const int*)d_in[1];
  const int*   batch = (const int*)d_in[2];
  const float* cwA[4]; const float* cbA[4]; const float* cwB[4]; const float* cbB[4];
  const float* bng[4]; const float* bnb[4];
  for (int l = 0; l < 4; l++){
    cwA[l] = (const float*)d_in[3 + l*6 + 0];
    cbA[l] = (const float*)d_in[3 + l*6 + 1];
    cwB[l] = (const float*)d_in[3 + l*6 + 2];
    cbB[l] = (const float*)d_in[3 + l*6 + 3];
    bng[l] = (const float*)d_in[3 + l*6 + 4];
    bnb[l] = (const float*)d_in[3 + l*6 + 5];
  }
  const float* fc1w = (const float*)d_in[27];
  const float* fc1b = (const float*)d_in[28];
  const float* fcg  = (const float*)d_in[29];
  const float* fcb  = (const float*)d_in[30];
  const float* fc2w = (const float*)d_in[31];
  const float* fc2b = (const float*)d_in[32];

  char* p = (char*)d_ws;
  auto alloc = [&](size_t bytes)->char* {
    char* r = p; p += (bytes + 511) & ~(size_t)511; return r;
  };
  int* deg     = (int*)alloc((size_t)N_NODES*4);
  int* offsets = (int*)alloc((size_t)(N_NODES+1)*4);
  int* cursor  = (int*)alloc((size_t)N_NODES*4);
  int* bsum    = (int*)alloc((size_t)SCAN_B*4);
  int* csr     = (int*)alloc((size_t)N_EDGES*4);
  float* bufA  = (float*)alloc((size_t)PADN*128*4);
  float* bufB  = (float*)alloc((size_t)PADN*128*4);
  float* bufC  = (float*)alloc((size_t)PADN*128*4);
  float* stats = (float*)alloc((size_t)(4*256 + NGRAPH*128 + NGRAPH*128)*4);
  float* pooled = stats + 4*256;
  float* z1     = pooled + NGRAPH*128;

  hipMemsetAsync(deg, 0, (size_t)N_NODES*4, stream);
  hipMemsetAsync(stats, 0, (size_t)(4*256 + NGRAPH*128)*4, stream);

  hist_kernel<<<(N_EDGES+255)/256, 256, 0, stream>>>(ei + N_EDGES, deg);
  blocksum_kernel<<<SCAN_B, 256, 0, stream>>>(deg, bsum);
  scan2_kernel<<<SCAN_B, 256, 0, stream>>>(deg, bsum, offsets, cursor);
  fill_kernel<<<(N_EDGES+255)/256, 256, 0, stream>>>(ei, ei + N_EDGES, cursor, csr);

  dim3 gg(PADN/64, 2);
  const float* hcur = x;
  for (int l = 0; l < 4; l++){
    aggregate_kernel<<<(N_NODES+3)/4, 256, 0, stream>>>(hcur, offsets, csr, bufB);
    gemm_leaky_kernel<false><<<gg, 256, 0, stream>>>(bufB, cwA[l], cbA[l], bufC, N_NODES, nullptr);
    gemm_leaky_kernel<true ><<<gg, 256, 0, stream>>>(bufC, cwB[l], cbB[l], bufA, N_NODES, stats + l*256);
    if (l < 3){
      normalize_kernel<<<1024, 256, 0, stream>>>(bufA, stats + l*256, bng[l], bnb[l]);
      hcur = bufA;
    }
  }

  pool_kernel<<<NGRAPH*8, 128, 0, stream>>>(bufA, batch, stats + 3*256, bng[3], bnb[3], pooled);
  fc1_kernel<<<NGRAPH, 128, 0, stream>>>(pooled, batch, fc1w, fc1b, z1);
  head2_kernel<<<1, 256, 0, stream>>>(z1, fcg, fcb, fc2w, fc2b, (float*)d_out);
}

// Round 3
// 619.425 us; speedup vs baseline: 1.8268x; 1.2532x over previous
//
#include <hip/hip_runtime.h>

#define N_NODES 50000
#define N_EDGES 800000
#define NGRAPH 64
#define OUTDIM 10
#define NEG 0.1f
#define BN_EPS 1e-5f
#define PADN 50048      // N rounded up to 64
#define NTILES 782      // PADN/64
#define SCAN_B 196      // ceil(N_NODES/256)

typedef __attribute__((ext_vector_type(8))) short bf16x8;
typedef __attribute__((ext_vector_type(4))) float f32x4;

static __device__ __forceinline__ float leaky(float x){ return x >= 0.f ? x : NEG*x; }

static __device__ __forceinline__ unsigned short f2bf(float f){
  unsigned u = __builtin_bit_cast(unsigned, f);
  u += 0x7fff + ((u >> 16) & 1);            // round-to-nearest-even
  return (unsigned short)(u >> 16);
}
static __device__ __forceinline__ float bf2f(unsigned short h){
  unsigned u = ((unsigned)h) << 16;
  return __builtin_bit_cast(float, u);
}
// split-packed element: high16 = bf16(a), low16 = bf16(a - hi)
static __device__ __forceinline__ unsigned packsp(float a){
  unsigned short hb = f2bf(a);
  unsigned short lb = f2bf(a - bf2f(hb));
  return (((unsigned)hb) << 16) | lb;
}

__device__ __forceinline__ int lb_search(const int* a, int n, int v){
  int lo = 0, hi = n;
  while (lo < hi){ int m = (lo+hi)>>1; if (a[m] < v) lo = m+1; else hi = m; }
  return lo;
}

// ---------------- CSR build ----------------
__global__ __launch_bounds__(256) void hist_kernel(const int* __restrict__ dst, int* __restrict__ deg){
  int e = blockIdx.x*256 + threadIdx.x;
  if (e < N_EDGES) atomicAdd(&deg[dst[e]], 1);
}

__global__ __launch_bounds__(256) void blocksum_kernel(const int* __restrict__ deg, int* __restrict__ bsum){
  __shared__ int red[256];
  int i = blockIdx.x*256 + threadIdx.x;
  red[threadIdx.x] = (i < N_NODES) ? deg[i] : 0;
  __syncthreads();
  for (int off = 128; off > 0; off >>= 1){
    if (threadIdx.x < off) red[threadIdx.x] += red[threadIdx.x + off];
    __syncthreads();
  }
  if (threadIdx.x == 0) bsum[blockIdx.x] = red[0];
}

__global__ __launch_bounds__(256) void scan2_kernel(const int* __restrict__ deg, const int* __restrict__ bsum,
        int* __restrict__ offsets, int* __restrict__ cursor){
  __shared__ int pre[256];
  __shared__ int sc[256];
  const int b = blockIdx.x, t = threadIdx.x;
  pre[t] = (t < b) ? bsum[t] : 0;
  __syncthreads();
  for (int off = 128; off > 0; off >>= 1){
    if (t < off) pre[t] += pre[t + off];
    __syncthreads();
  }
  const int base = pre[0];
  const int i = b*256 + t;
  const int v = (i < N_NODES) ? deg[i] : 0;
  sc[t] = v; __syncthreads();
  for (int off = 1; off < 256; off <<= 1){
    int add = (t >= off) ? sc[t-off] : 0;
    __syncthreads();
    sc[t] += add;
    __syncthreads();
  }
  if (i < N_NODES){
    int off_ = base + sc[t] - v;
    offsets[i] = off_; cursor[i] = off_;
  }
  if (b == SCAN_B-1 && t == 255) offsets[N_NODES] = base + sc[255];
}

__global__ __launch_bounds__(256) void fill_kernel(const int* __restrict__ src, const int* __restrict__ dst,
        int* __restrict__ cursor, int* __restrict__ col){
  int e = blockIdx.x*256 + threadIdx.x;
  if (e < N_EDGES){
    int d = dst[e];
    int pos = atomicAdd(&cursor[d], 1);
    col[pos] = src[e];
  }
}

// ---------------- weight prep: transpose + hi/lo split, [mat][n][k] bf16 ----------------
__global__ __launch_bounds__(128) void convw_kernel(
    const float* __restrict__ w0, const float* __restrict__ w1,
    const float* __restrict__ w2, const float* __restrict__ w3,
    const float* __restrict__ w4, const float* __restrict__ w5,
    const float* __restrict__ w6, const float* __restrict__ w7,
    unsigned short* __restrict__ WtH, unsigned short* __restrict__ WtL){
  const float* W;
  switch(blockIdx.x){
    case 0: W=w0; break; case 1: W=w1; break; case 2: W=w2; break; case 3: W=w3; break;
    case 4: W=w4; break; case 5: W=w5; break; case 6: W=w6; break; default: W=w7; break;
  }
  const int n = threadIdx.x;
  unsigned short* oh = WtH + (size_t)blockIdx.x*16384 + n*128;
  unsigned short* ol = WtL + (size_t)blockIdx.x*16384 + n*128;
  for (int k0 = 0; k0 < 128; k0 += 32){
    __align__(16) unsigned short hh[32], ll[32];
    #pragma unroll
    for (int i = 0; i < 32; i++){
      float a = W[(size_t)(k0+i)*128 + n];       // coalesced across lanes
      unsigned short hb = f2bf(a);
      hh[i] = hb;
      ll[i] = f2bf(a - bf2f(hb));
    }
    #pragma unroll
    for (int q = 0; q < 4; q++){
      *(uint4*)(oh + k0 + q*8) = *(const uint4*)&hh[q*8];
      *(uint4*)(ol + k0 + q*8) = *(const uint4*)&ll[q*8];
    }
  }
}

// ---------------- GIN aggregation (+ fused BN/leaky of the PREVIOUS layer on the fly) --------
// out[v] = f(h[v]) + sum_u f(h[u]);  f = identity (layer 1) or leaky(bn(.)).
// Output in split-packed u32 format.
template<bool BNIN>
__global__ __launch_bounds__(256) void aggregate_kernel(const float* __restrict__ h,
        const int* __restrict__ offsets, const int* __restrict__ col,
        const float* __restrict__ stats, const float* __restrict__ g, const float* __restrict__ b,
        unsigned* __restrict__ outSP){
  int v = (blockIdx.x*256 + threadIdx.x) >> 6;   // one wave per node
  int lane = threadIdx.x & 63;
  if (v >= N_NODES) return;
  float sc0 = 1.f, sh0 = 0.f, sc1 = 1.f, sh1 = 0.f;
  if (BNIN){
    int c0 = lane*2, c1 = lane*2 + 1;
    float su0 = stats[c0]     + stats[256+c0] + stats[512+c0] + stats[768+c0];
    float qu0 = stats[128+c0] + stats[384+c0] + stats[640+c0] + stats[896+c0];
    float su1 = stats[c1]     + stats[256+c1] + stats[512+c1] + stats[768+c1];
    float qu1 = stats[128+c1] + stats[384+c1] + stats[640+c1] + stats[896+c1];
    float mu0 = su0*(1.f/N_NODES), var0 = qu0*(1.f/N_NODES) - mu0*mu0;
    float mu1 = su1*(1.f/N_NODES), var1 = qu1*(1.f/N_NODES) - mu1*mu1;
    sc0 = g[c0]*rsqrtf(var0+BN_EPS); sh0 = b[c0] - mu0*sc0;
    sc1 = g[c1]*rsqrtf(var1+BN_EPS); sh1 = b[c1] - mu1*sc1;
  }
  const float2* hp = (const float2*)h;
  int s = offsets[v], e = offsets[v+1];
  float2 t = hp[(size_t)v*64 + lane];
  float ax, ay;
  if (BNIN){ ax = leaky(t.x*sc0+sh0); ay = leaky(t.y*sc1+sh1); }
  else     { ax = t.x; ay = t.y; }
  int j = s;
  for (; j + 4 <= e; j += 4){
    int u0 = col[j], u1 = col[j+1], u2 = col[j+2], u3 = col[j+3];
    float2 t0 = hp[(size_t)u0*64 + lane];
    float2 t1 = hp[(size_t)u1*64 + lane];
    float2 t2 = hp[(size_t)u2*64 + lane];
    float2 t3 = hp[(size_t)u3*64 + lane];
    if (BNIN){
      ax += leaky(t0.x*sc0+sh0) + leaky(t1.x*sc0+sh0) + leaky(t2.x*sc0+sh0) + leaky(t3.x*sc0+sh0);
      ay += leaky(t0.y*sc1+sh1) + leaky(t1.y*sc1+sh1) + leaky(t2.y*sc1+sh1) + leaky(t3.y*sc1+sh1);
    } else {
      ax += (t0.x + t1.x) + (t2.x + t3.x);
      ay += (t0.y + t1.y) + (t2.y + t3.y);
    }
  }
  for (; j < e; j++){
    int u = col[j];
    float2 tu = hp[(size_t)u*64 + lane];
    if (BNIN){ ax += leaky(tu.x*sc0+sh0); ay += leaky(tu.y*sc1+sh1); }
    else     { ax += tu.x; ay += tu.y; }
  }
  uint2 o; o.x = packsp(ax); o.y = packsp(ay);
  ((uint2*)outSP)[(size_t)v*64 + lane] = o;
}

// ---------------- MFMA GEMM: (N x 128 SP) @ (128 x 128) + bias + leaky ----------------
// split-bf16: a*w ~= ah*wh + ah*wl + al*wh (fp32 MFMA accumulate).
// 64x64 tile/block (blockIdx.y = col half), 256 threads = 4 waves x 16 rows.
// POST: writes fp32 h_raw + fused BN stats (4-way split atomics). PRE: writes SP plane.
template<bool POST>
__global__ __launch_bounds__(256) void gemm_kernel(const unsigned* __restrict__ Asp,
      const unsigned short* __restrict__ WtHg, const unsigned short* __restrict__ WtLg,
      const float* __restrict__ bias,
      unsigned* __restrict__ outSP, float* __restrict__ outF, float* __restrict__ stats){
  __shared__ __align__(16) unsigned short Ah[64*128];
  __shared__ __align__(16) unsigned short Al[64*128];
  __shared__ __align__(16) unsigned short Wh[64*128];
  __shared__ __align__(16) unsigned short Wl[64*128];
  const int tid = threadIdx.x;
  const int row0 = blockIdx.x*64;
  const int co = blockIdx.y*64;

  { // W staging: rows co..co+63 of [n][k] planes, XOR-swizzled
    const uint4* gh = (const uint4*)(WtHg + (size_t)co*128);
    const uint4* gl = (const uint4*)(WtLg + (size_t)co*128);
    char* lh = (char*)Wh; char* ll = (char*)Wl;
    #pragma unroll
    for (int i = 0; i < 4; i++){
      int idx = tid + i*256;                 // 0..1023
      int n = idx >> 4, kq = idx & 15;
      int off = (n*256 + kq*16) ^ ((n&7)<<4);
      *(uint4*)(lh + off) = gh[idx];
      *(uint4*)(ll + off) = gl[idx];
    }
  }
  { // A staging: unpack SP -> hi/lo bf16, XOR-swizzled
    const uint4* ga = (const uint4*)(Asp + (size_t)row0*128);
    #pragma unroll
    for (int i = 0; i < 8; i++){
      int idx = tid + i*256;                 // 0..2047
      int r = idx >> 5, cq = idx & 31;
      uint4 p = ga[idx];
      ushort4 hh, lo4;
      hh.x = (unsigned short)(p.x>>16); lo4.x = (unsigned short)p.x;
      hh.y = (unsigned short)(p.y>>16); lo4.y = (unsigned short)p.y;
      hh.z = (unsigned short)(p.z>>16); lo4.z = (unsigned short)p.z;
      hh.w = (unsigned short)(p.w>>16); lo4.w = (unsigned short)p.w;
      int off = (r*256 + cq*8) ^ ((r&7)<<4);
      *(ushort4*)((char*)Ah + off) = hh;
      *(ushort4*)((char*)Al + off) = lo4;
    }
  }
  __syncthreads();

  const int w = tid >> 6, l = tid & 63;
  const int lr = l & 15, lg = l >> 4;
  f32x4 acc[4];
  #pragma unroll
  for (int ct = 0; ct < 4; ct++) acc[ct] = (f32x4){0.f,0.f,0.f,0.f};
  const int arow = w*16 + lr;
  const int aswz = (arow&7) << 4;
  #pragma unroll
  for (int kb = 0; kb < 4; kb++){
    const int koff = kb*64 + lg*16;
    bf16x8 a_h = *(const bf16x8*)((char*)Ah + ((arow*256 + koff) ^ aswz));
    bf16x8 a_l = *(const bf16x8*)((char*)Al + ((arow*256 + koff) ^ aswz));
    #pragma unroll
    for (int ct = 0; ct < 4; ct++){
      const int wrow = ct*16 + lr;
      const int woff = (wrow*256 + koff) ^ ((wrow&7)<<4);
      bf16x8 w_h = *(const bf16x8*)((char*)Wh + woff);
      bf16x8 w_l = *(const bf16x8*)((char*)Wl + woff);
      acc[ct] = __builtin_amdgcn_mfma_f32_16x16x32_bf16(a_h, w_h, acc[ct], 0, 0, 0);
      acc[ct] = __builtin_amdgcn_mfma_f32_16x16x32_bf16(a_h, w_l, acc[ct], 0, 0, 0);
      acc[ct] = __builtin_amdgcn_mfma_f32_16x16x32_bf16(a_l, w_h, acc[ct], 0, 0, 0);
    }
  }

  // epilogue: C/D layout col = l&15, row = (l>>4)*4 + reg  [m89]
  float sA[4], qA[4];
  #pragma unroll
  for (int ct = 0; ct < 4; ct++){
    int gcol = co + ct*16 + lr;
    float bv = bias[gcol];
    float s = 0.f, q = 0.f;
    #pragma unroll
    for (int r = 0; r < 4; r++){
      int grow = row0 + w*16 + lg*4 + r;
      if (grow < N_NODES){
        float o = leaky(acc[ct][r] + bv);
        if (POST){
          outF[(size_t)grow*128 + gcol] = o;
          s += o; q += o*o;
        } else {
          outSP[(size_t)grow*128 + gcol] = packsp(o);
        }
      }
    }
    if (POST){
      s += __shfl_xor(s, 16, 64); s += __shfl_xor(s, 32, 64);
      q += __shfl_xor(q, 16, 64); q += __shfl_xor(q, 32, 64);
      sA[ct] = s; qA[ct] = q;
    }
  }
  if (POST){
    __syncthreads();                          // all LDS reads done; reuse Ah as scratch
    float* redS = (float*)Ah;                 // [64][4]
    float* redQ = redS + 256;
    if (lg == 0){
      #pragma unroll
      for (int ct = 0; ct < 4; ct++){
        redS[(ct*16+lr)*4 + w] = sA[ct];
        redQ[(ct*16+lr)*4 + w] = qA[ct];
      }
    }
    __syncthreads();
    if (tid < 64){
      float S = redS[tid*4] + redS[tid*4+1] + redS[tid*4+2] + redS[tid*4+3];
      float Q = redQ[tid*4] + redQ[tid*4+1] + redQ[tid*4+2] + redQ[tid*4+3];
      float* st = stats + (blockIdx.x & 3)*256;   // 4-way split to cut atomic contention
      atomicAdd(&st[co + tid], S);
      atomicAdd(&st[128 + co + tid], Q);
    }
  }
}

// ---------------- pooling with fused BN+leaky (layer 4) ----------------
__global__ __launch_bounds__(128) void pool_kernel(const float* __restrict__ h,
      const int* __restrict__ batch, const float* __restrict__ stats,
      const float* __restrict__ g, const float* __restrict__ b, float* __restrict__ pooled){
  int gi = blockIdx.x >> 3, part = blockIdx.x & 7;
  int c = threadIdx.x;
  float su = stats[c]     + stats[256+c] + stats[512+c] + stats[768+c];
  float qu = stats[128+c] + stats[384+c] + stats[640+c] + stats[896+c];
  float mu = su*(1.f/N_NODES), var = qu*(1.f/N_NODES) - mu*mu;
  float sc = g[c]*rsqrtf(var+BN_EPS), sh = b[c] - mu*sc;
  int s0 = lb_search(batch, N_NODES, gi), e0 = lb_search(batch, N_NODES, gi+1);
  int len = e0 - s0;
  int a  = s0 + ((len*part) >> 3);
  int b2 = s0 + ((len*(part+1)) >> 3);
  float acc = 0.f;
  for (int r = a; r < b2; r++) acc += leaky(h[(size_t)r*128 + c]*sc + sh);
  atomicAdd(&pooled[gi*128 + c], acc);
}

// ---------------- head ----------------
__global__ __launch_bounds__(128) void fc1_kernel(const float* __restrict__ pooled,
      const int* __restrict__ batch, const float* __restrict__ fc1w,
      const float* __restrict__ fc1b, float* __restrict__ z1){
  __shared__ float ps[128];
  __shared__ float invs;
  const int gi = blockIdx.x, t = threadIdx.x;
  if (t == 0){
    int s = lb_search(batch, N_NODES, gi), e = lb_search(batch, N_NODES, gi+1);
    invs = 1.f / fmaxf((float)(e - s), 1.f);
  }
  ps[t] = pooled[gi*128 + t];
  __syncthreads();
  float inv = invs;
  float acc = 0.f;
  #pragma unroll 8
  for (int k = 0; k < 128; k++) acc += ps[k]*fc1w[k*128 + t];
  z1[gi*128 + t] = acc*inv + fc1b[t];
}

__global__ __launch_bounds__(256) void head2_kernel(const float* __restrict__ z1,
      const float* __restrict__ g, const float* __restrict__ b,
      const float* __restrict__ fc2w, const float* __restrict__ fc2b,
      float* __restrict__ out){
  __shared__ float z[64*128];
  __shared__ float sc_s[128], sh_s[128];
  const int t = threadIdx.x;
  for (int i = t; i < 8192; i += 256) z[i] = z1[i];
  __syncthreads();
  if (t < 128){
    float s = 0.f, q = 0.f;
    for (int r = 0; r < 64; r++){ float v = z[r*128 + t]; s += v; q += v*v; }
    float mu = s*(1.f/64.f), var = q*(1.f/64.f) - mu*mu;
    float scv = g[t] * rsqrtf(var + BN_EPS);
    sc_s[t] = scv; sh_s[t] = b[t] - mu*scv;
  }
  __syncthreads();
  for (int i = t; i < 8192; i += 256){ int c = i & 127; z[i] = leaky(z[i]*sc_s[c] + sh_s[c]); }
  __syncthreads();
  for (int o = t; o < NGRAPH*OUTDIM; o += 256){
    int row = o/OUTDIM, c = o - row*OUTDIM;
    float acc = fc2b[c];
    for (int k = 0; k < 128; k++) acc += z[row*128 + k]*fc2w[k*OUTDIM + c];
    out[o] = acc;
  }
}

extern "C" void kernel_launch(void* const* d_in, const int* in_sizes, int n_in,
                              void* d_out, int out_size, void* d_ws, size_t ws_size,
                              hipStream_t stream){
  (void)in_sizes; (void)n_in; (void)out_size; (void)ws_size;
  const float* x     = (const float*)d_in[0];
  const int*   ei    = (const int*)d_in[1];
  const int*   batch = (const int*)d_in[2];
  const float* cwA[4]; const float* cbA[4]; const float* cwB[4]; const float* cbB[4];
  const float* bng[4]; const float* bnb[4];
  for (int l = 0; l < 4; l++){
    cwA[l] = (const float*)d_in[3 + l*6 + 0];
    cbA[l] = (const float*)d_in[3 + l*6 + 1];
    cwB[l] = (const float*)d_in[3 + l*6 + 2];
    cbB[l] = (const float*)d_in[3 + l*6 + 3];
    bng[l] = (const float*)d_in[3 + l*6 + 4];
    bnb[l] = (const float*)d_in[3 + l*6 + 5];
  }
  const float* fc1w = (const float*)d_in[27];
  const float* fc1b = (const float*)d_in[28];
  const float* fcg  = (const float*)d_in[29];
  const float* fcb  = (const float*)d_in[30];
  const float* fc2w = (const float*)d_in[31];
  const float* fc2b = (const float*)d_in[32];

  char* p = (char*)d_ws;
  auto alloc = [&](size_t bytes)->char* {
    char* r = p; p += (bytes + 511) & ~(size_t)511; return r;
  };
  int* deg     = (int*)alloc((size_t)N_NODES*4);
  int* offsets = (int*)alloc((size_t)(N_NODES+1)*4);
  int* cursor  = (int*)alloc((size_t)N_NODES*4);
  int* bsum    = (int*)alloc((size_t)SCAN_B*4);
  int* csr     = (int*)alloc((size_t)N_EDGES*4);
  unsigned short* WtH = (unsigned short*)alloc((size_t)8*16384*2);
  unsigned short* WtL = (unsigned short*)alloc((size_t)8*16384*2);
  unsigned* spB = (unsigned*)alloc((size_t)PADN*128*4);
  unsigned* spC = (unsigned*)alloc((size_t)PADN*128*4);
  float* hraw   = (float*)alloc((size_t)PADN*128*4);
  float* stats  = (float*)alloc((size_t)(4*1024 + 8192 + 8192)*4);
  float* pooled = stats + 4*1024;
  float* z1     = pooled + 8192;

  hipMemsetAsync(deg, 0, (size_t)N_NODES*4, stream);
  hipMemsetAsync(stats, 0, (size_t)(4*1024 + 8192)*4, stream);
  hipMemsetAsync(spB + (size_t)N_NODES*128, 0, (size_t)(PADN-N_NODES)*128*4, stream);
  hipMemsetAsync(spC + (size_t)N_NODES*128, 0, (size_t)(PADN-N_NODES)*128*4, stream);

  convw_kernel<<<8, 128, 0, stream>>>(cwA[0], cwB[0], cwA[1], cwB[1],
                                      cwA[2], cwB[2], cwA[3], cwB[3], WtH, WtL);
  hist_kernel<<<(N_EDGES+255)/256, 256, 0, stream>>>(ei + N_EDGES, deg);
  blocksum_kernel<<<SCAN_B, 256, 0, stream>>>(deg, bsum);
  scan2_kernel<<<SCAN_B, 256, 0, stream>>>(deg, bsum, offsets, cursor);
  fill_kernel<<<(N_EDGES+255)/256, 256, 0, stream>>>(ei, ei + N_EDGES, cursor, csr);

  dim3 gg(NTILES, 2);
  for (int l = 0; l < 4; l++){
    if (l == 0)
      aggregate_kernel<false><<<12500, 256, 0, stream>>>(x, offsets, csr,
            stats, bng[0], bnb[0], spB);
    else
      aggregate_kernel<true><<<12500, 256, 0, stream>>>(hraw, offsets, csr,
            stats + (l-1)*1024, bng[l-1], bnb[l-1], spB);
    // Wa = matrix 2l, Wb = matrix 2l+1 in the packed Wt planes
    gemm_kernel<false><<<gg, 256, 0, stream>>>(spB, WtH + (size_t)(2*l)*16384,
            WtL + (size_t)(2*l)*16384, cbA[l], spC, nullptr, nullptr);
    gemm_kernel<true><<<gg, 256, 0, stream>>>(spC, WtH + (size_t)(2*l+1)*16384,
            WtL + (size_t)(2*l+1)*16384, cbB[l], nullptr, hraw, stats + l*1024);
  }

  pool_kernel<<<NGRAPH*8, 128, 0, stream>>>(hraw, batch, stats + 3*1024, bng[3], bnb[3], pooled);
  fc1_kernel<<<NGRAPH, 128, 0, stream>>>(pooled, batch, fc1w, fc1b, z1);
  head2_kernel<<<1, 256, 0, stream>>>(z1, fcg, fcb, fc2w, fc2b, (float*)d_out);
}

// Round 4
// 618.180 us; speedup vs baseline: 1.8305x; 1.0020x over previous
//
#include <hip/hip_runtime.h>

#define N_NODES 50000
#define N_EDGES 800000
#define NGRAPH 64
#define OUTDIM 10
#define NEG 0.1f
#define BN_EPS 1e-5f
#define PADN 50048      // N rounded up to 64
#define NTILES 782      // PADN/64
#define SCAN_B 196      // ceil(N_NODES/256)

typedef __attribute__((ext_vector_type(8))) short bf16x8;
typedef __attribute__((ext_vector_type(4))) float f32x4;
typedef __attribute__((ext_vector_type(4))) unsigned u32x4;

static __device__ __forceinline__ float leaky(float x){ return fmaxf(x, NEG*x); }

static __device__ __forceinline__ unsigned short f2bf(float f){
  unsigned u = __builtin_bit_cast(unsigned, f);
  u += 0x7fff + ((u >> 16) & 1);            // round-to-nearest-even
  return (unsigned short)(u >> 16);
}
static __device__ __forceinline__ float bf2f(unsigned short h){
  unsigned u = ((unsigned)h) << 16;
  return __builtin_bit_cast(float, u);
}
// split-packed element: high16 = bf16(a), low16 = bf16(a - hi)
static __device__ __forceinline__ unsigned packsp(float a){
  unsigned short hb = f2bf(a);
  unsigned short lb = f2bf(a - bf2f(hb));
  return (((unsigned)hb) << 16) | lb;
}
// bf16 pair unpack from u32 (lo16 = even feature, hi16 = odd feature)
static __device__ __forceinline__ float bplo(unsigned u){ return __builtin_bit_cast(float, u << 16); }
static __device__ __forceinline__ float bphi(unsigned u){ return __builtin_bit_cast(float, u & 0xFFFF0000u); }

__device__ __forceinline__ int lb_search(const int* a, int n, int v){
  int lo = 0, hi = n;
  while (lo < hi){ int m = (lo+hi)>>1; if (a[m] < v) lo = m+1; else hi = m; }
  return lo;
}

// ---------------- CSR build ----------------
__global__ __launch_bounds__(256) void hist_kernel(const int* __restrict__ dst, int* __restrict__ deg){
  int e = blockIdx.x*256 + threadIdx.x;
  if (e < N_EDGES) atomicAdd(&deg[dst[e]], 1);
}

__global__ __launch_bounds__(256) void blocksum_kernel(const int* __restrict__ deg, int* __restrict__ bsum){
  __shared__ int red[256];
  int i = blockIdx.x*256 + threadIdx.x;
  red[threadIdx.x] = (i < N_NODES) ? deg[i] : 0;
  __syncthreads();
  for (int off = 128; off > 0; off >>= 1){
    if (threadIdx.x < off) red[threadIdx.x] += red[threadIdx.x + off];
    __syncthreads();
  }
  if (threadIdx.x == 0) bsum[blockIdx.x] = red[0];
}

__global__ __launch_bounds__(256) void scan2_kernel(const int* __restrict__ deg, const int* __restrict__ bsum,
        int* __restrict__ offsets, int* __restrict__ cursor){
  __shared__ int pre[256];
  __shared__ int sc[256];
  const int b = blockIdx.x, t = threadIdx.x;
  pre[t] = (t < b) ? bsum[t] : 0;
  __syncthreads();
  for (int off = 128; off > 0; off >>= 1){
    if (t < off) pre[t] += pre[t + off];
    __syncthreads();
  }
  const int base = pre[0];
  const int i = b*256 + t;
  const int v = (i < N_NODES) ? deg[i] : 0;
  sc[t] = v; __syncthreads();
  for (int off = 1; off < 256; off <<= 1){
    int add = (t >= off) ? sc[t-off] : 0;
    __syncthreads();
    sc[t] += add;
    __syncthreads();
  }
  if (i < N_NODES){
    int off_ = base + sc[t] - v;
    offsets[i] = off_; cursor[i] = off_;
  }
  if (b == SCAN_B-1 && t == 255) offsets[N_NODES] = base + sc[255];
}

__global__ __launch_bounds__(256) void fill_kernel(const int* __restrict__ src, const int* __restrict__ dst,
        int* __restrict__ cursor, int* __restrict__ col){
  int e = blockIdx.x*256 + threadIdx.x;
  if (e < N_EDGES){
    int d = dst[e];
    int pos = atomicAdd(&cursor[d], 1);
    col[pos] = src[e];
  }
}

// ---------------- x -> bf16 plane ----------------
__global__ __launch_bounds__(256) void convx_kernel(const float* __restrict__ x, unsigned short* __restrict__ hbf){
  int i = blockIdx.x*256 + threadIdx.x;           // one float4 each
  if (i < N_NODES*32){
    float4 v = ((const float4*)x)[i];
    ushort4 o;
    o.x = f2bf(v.x); o.y = f2bf(v.y); o.z = f2bf(v.z); o.w = f2bf(v.w);
    ((ushort4*)hbf)[i] = o;
  }
}

// ---------------- weight prep: MFMA-fragment-ordered hi/lo planes ----------------
// Wfrag per matrix: [plane(2)][frag(2048)][8] bf16;  frag = (kb*8+ct)*64 + l
// element j of frag = W[k = kb*32 + (l>>4)*8 + j][n = ct*16 + (l&15)]
__global__ __launch_bounds__(256) void convw_kernel(
    const float* __restrict__ w0, const float* __restrict__ w1,
    const float* __restrict__ w2, const float* __restrict__ w3,
    const float* __restrict__ w4, const float* __restrict__ w5,
    const float* __restrict__ w6, const float* __restrict__ w7,
    unsigned short* __restrict__ Wfrag){
  const float* W;
  switch(blockIdx.x){
    case 0: W=w0; break; case 1: W=w1; break; case 2: W=w2; break; case 3: W=w3; break;
    case 4: W=w4; break; case 5: W=w5; break; case 6: W=w6; break; default: W=w7; break;
  }
  unsigned short* oh = Wfrag + (size_t)blockIdx.x*32768;
  unsigned short* ol = oh + 16384;
  for (int i = 0; i < 8; i++){
    int f = threadIdx.x*8 + i;
    int l = f & 63, ct = (f>>6) & 7, kb = f>>9;
    __align__(16) unsigned short hh[8], ll[8];
    #pragma unroll
    for (int j = 0; j < 8; j++){
      int k = kb*32 + (l>>4)*8 + j;
      int n = ct*16 + (l&15);
      float a = W[(size_t)k*128 + n];
      unsigned short hb = f2bf(a);
      hh[j] = hb;
      ll[j] = f2bf(a - bf2f(hb));
    }
    *(uint4*)(oh + (size_t)f*8) = *(const uint4*)hh;
    *(uint4*)(ol + (size_t)f*8) = *(const uint4*)ll;
  }
}

// ---------------- GIN aggregation over bf16 plane (+ fused BN/leaky of prev layer) --------
// out[v] = f(h[v]) + sum_u f(h[u]);  f = identity (layer 1) or leaky(bn(.)). Output SP u32.
template<bool BNIN>
__global__ __launch_bounds__(256) void aggregate_kernel(const unsigned* __restrict__ hbf,
        const int* __restrict__ offsets, const int* __restrict__ col,
        const float* __restrict__ stats, const float* __restrict__ g, const float* __restrict__ b,
        uint2* __restrict__ outSP){
  int v = (blockIdx.x*256 + threadIdx.x) >> 6;   // one wave per node
  int lane = threadIdx.x & 63;
  if (v >= N_NODES) return;
  float sc0 = 1.f, sh0 = 0.f, sc1 = 1.f, sh1 = 0.f;
  if (BNIN){
    int c0 = lane*2, c1 = c0 + 1;
    float su0=0.f, qu0=0.f, su1=0.f, qu1=0.f;
    #pragma unroll
    for (int s8 = 0; s8 < 8; s8++){
      su0 += stats[s8*256 + c0];       qu0 += stats[s8*256 + 128 + c0];
      su1 += stats[s8*256 + c1];       qu1 += stats[s8*256 + 128 + c1];
    }
    float mu0 = su0*(1.f/N_NODES), var0 = qu0*(1.f/N_NODES) - mu0*mu0;
    float mu1 = su1*(1.f/N_NODES), var1 = qu1*(1.f/N_NODES) - mu1*mu1;
    sc0 = g[c0]*rsqrtf(var0+BN_EPS); sh0 = b[c0] - mu0*sc0;
    sc1 = g[c1]*rsqrtf(var1+BN_EPS); sh1 = b[c1] - mu1*sc1;
  }
  int s = offsets[v], e = offsets[v+1];
  unsigned u = hbf[(size_t)v*64 + lane];          // self term
  float ax, ay;
  if (BNIN){ ax = leaky(bplo(u)*sc0+sh0); ay = leaky(bphi(u)*sc1+sh1); }
  else     { ax = bplo(u); ay = bphi(u); }
  int j = s;
  for (; j + 4 <= e; j += 4){                     // 4 gathers in flight
    int u0 = col[j], u1 = col[j+1], u2 = col[j+2], u3 = col[j+3];
    unsigned w0 = hbf[(size_t)u0*64 + lane];
    unsigned w1 = hbf[(size_t)u1*64 + lane];
    unsigned w2 = hbf[(size_t)u2*64 + lane];
    unsigned w3 = hbf[(size_t)u3*64 + lane];
    if (BNIN){
      ax += leaky(bplo(w0)*sc0+sh0) + leaky(bplo(w1)*sc0+sh0)
          + leaky(bplo(w2)*sc0+sh0) + leaky(bplo(w3)*sc0+sh0);
      ay += leaky(bphi(w0)*sc1+sh1) + leaky(bphi(w1)*sc1+sh1)
          + leaky(bphi(w2)*sc1+sh1) + leaky(bphi(w3)*sc1+sh1);
    } else {
      ax += (bplo(w0) + bplo(w1)) + (bplo(w2) + bplo(w3));
      ay += (bphi(w0) + bphi(w1)) + (bphi(w2) + bphi(w3));
    }
  }
  for (; j < e; j++){
    unsigned wv = hbf[(size_t)col[j]*64 + lane];
    if (BNIN){ ax += leaky(bplo(wv)*sc0+sh0); ay += leaky(bphi(wv)*sc1+sh1); }
    else     { ax += bplo(wv); ay += bphi(wv); }
  }
  uint2 o; o.x = packsp(ax); o.y = packsp(ay);
  outSP[(size_t)v*64 + lane] = o;
}

// ---------------- LDS-free MFMA GEMM: (N x 128 SP) @ (128 x 128) + bias + leaky ----------
// 256 thr = 4 waves; wave w: rows w*16..+15, all 128 cols. A direct from global (rows are
// wave-private), W from fragment-ordered planes (L2 broadcast). split-bf16 3-MFMA product.
template<bool POST>
__global__ __launch_bounds__(256) void gemm_kernel(const unsigned* __restrict__ Asp,
      const unsigned short* __restrict__ Wfrag,
      const float* __restrict__ bias,
      unsigned* __restrict__ outSP, unsigned short* __restrict__ outBF,
      float* __restrict__ stats){
  const int tid = threadIdx.x;
  const int w = tid >> 6, l = tid & 63, lr = l & 15, lg = l >> 4;
  const int rowA = blockIdx.x*64 + w*16 + lr;
  const u32x4* ap = (const u32x4*)(Asp + (size_t)rowA*128);
  const bf16x8* wh_p = (const bf16x8*)Wfrag;
  const bf16x8* wl_p = (const bf16x8*)(Wfrag + 16384);
  f32x4 acc[8];
  #pragma unroll
  for (int ct = 0; ct < 8; ct++) acc[ct] = (f32x4){0.f,0.f,0.f,0.f};

  #pragma unroll
  for (int kb = 0; kb < 4; kb++){
    u32x4 p0 = ap[kb*8 + lg*2];
    u32x4 p1 = ap[kb*8 + lg*2 + 1];
    u32x4 hv, lv;
    hv.x = (p0.y & 0xFFFF0000u) | (p0.x >> 16);
    hv.y = (p0.w & 0xFFFF0000u) | (p0.z >> 16);
    hv.z = (p1.y & 0xFFFF0000u) | (p1.x >> 16);
    hv.w = (p1.w & 0xFFFF0000u) | (p1.z >> 16);
    lv.x = (p0.y << 16) | (p0.x & 0xFFFFu);
    lv.y = (p0.w << 16) | (p0.z & 0xFFFFu);
    lv.z = (p1.y << 16) | (p1.x & 0xFFFFu);
    lv.w = (p1.w << 16) | (p1.z & 0xFFFFu);
    bf16x8 a_h = __builtin_bit_cast(bf16x8, hv);
    bf16x8 a_l = __builtin_bit_cast(bf16x8, lv);
    const int fb = kb*512 + l;
    #pragma unroll
    for (int ct = 0; ct < 8; ct++){
      bf16x8 w_h = wh_p[fb + ct*64];
      bf16x8 w_l = wl_p[fb + ct*64];
      acc[ct] = __builtin_amdgcn_mfma_f32_16x16x32_bf16(a_h, w_h, acc[ct], 0, 0, 0);
      acc[ct] = __builtin_amdgcn_mfma_f32_16x16x32_bf16(a_h, w_l, acc[ct], 0, 0, 0);
      acc[ct] = __builtin_amdgcn_mfma_f32_16x16x32_bf16(a_l, w_h, acc[ct], 0, 0, 0);
    }
  }

  // C/D layout: col = l&15, row = (l>>4)*4 + reg  [m89]
  const int rowO = blockIdx.x*64 + w*16 + lg*4;
  #pragma unroll
  for (int ct = 0; ct < 8; ct++){
    const int gcol = ct*16 + lr;
    const float bv = bias[gcol];
    float s = 0.f, q = 0.f;
    #pragma unroll
    for (int r = 0; r < 4; r++){
      int grow = rowO + r;
      float t = acc[ct][r] + bv;
      float o = fmaxf(t, NEG*t);
      if (grow < N_NODES){
        if (POST){
          outBF[(size_t)grow*128 + gcol] = f2bf(o);
          s += o; q += o*o;
        } else {
          outSP[(size_t)grow*128 + gcol] = packsp(o);
        }
      }
    }
    if (POST){
      s += __shfl_xor(s, 16, 64); s += __shfl_xor(s, 32, 64);
      q += __shfl_xor(q, 16, 64); q += __shfl_xor(q, 32, 64);
      if (lg == 0){
        float* st = stats + (blockIdx.x & 7)*256;    // 8-way split atomics
        atomicAdd(&st[gcol], s);
        atomicAdd(&st[128 + gcol], q);
      }
    }
  }
}

// ---------------- pooling with fused BN+leaky (layer 4, bf16 input) ----------------
__global__ __launch_bounds__(128) void pool_kernel(const unsigned short* __restrict__ hbf,
      const int* __restrict__ batch, const float* __restrict__ stats,
      const float* __restrict__ g, const float* __restrict__ b, float* __restrict__ pooled){
  int gi = blockIdx.x >> 3, part = blockIdx.x & 7;
  int c = threadIdx.x;
  float su = 0.f, qu = 0.f;
  #pragma unroll
  for (int s8 = 0; s8 < 8; s8++){ su += stats[s8*256 + c]; qu += stats[s8*256 + 128 + c]; }
  float mu = su*(1.f/N_NODES), var = qu*(1.f/N_NODES) - mu*mu;
  float sc = g[c]*rsqrtf(var+BN_EPS), sh = b[c] - mu*sc;
  int s0 = lb_search(batch, N_NODES, gi), e0 = lb_search(batch, N_NODES, gi+1);
  int len = e0 - s0;
  int a  = s0 + ((len*part) >> 3);
  int b2 = s0 + ((len*(part+1)) >> 3);
  float acc = 0.f;
  for (int r = a; r < b2; r++){
    float t = bf2f(hbf[(size_t)r*128 + c])*sc + sh;
    acc += fmaxf(t, NEG*t);
  }
  atomicAdd(&pooled[gi*128 + c], acc);
}

// ---------------- head ----------------
__global__ __launch_bounds__(128) void fc1_kernel(const float* __restrict__ pooled,
      const int* __restrict__ batch, const float* __restrict__ fc1w,
      const float* __restrict__ fc1b, float* __restrict__ z1){
  __shared__ float ps[128];
  __shared__ float invs;
  const int gi = blockIdx.x, t = threadIdx.x;
  if (t == 0){
    int s = lb_search(batch, N_NODES, gi), e = lb_search(batch, N_NODES, gi+1);
    invs = 1.f / fmaxf((float)(e - s), 1.f);
  }
  ps[t] = pooled[gi*128 + t];
  __syncthreads();
  float inv = invs;
  float acc = 0.f;
  #pragma unroll 8
  for (int k = 0; k < 128; k++) acc += ps[k]*fc1w[k*128 + t];
  z1[gi*128 + t] = acc*inv + fc1b[t];
}

__global__ __launch_bounds__(256) void head2_kernel(const float* __restrict__ z1,
      const float* __restrict__ g, const float* __restrict__ b,
      const float* __restrict__ fc2w, const float* __restrict__ fc2b,
      float* __restrict__ out){
  __shared__ float z[64*128];
  __shared__ float sc_s[128], sh_s[128];
  const int t = threadIdx.x;
  for (int i = t; i < 8192; i += 256) z[i] = z1[i];
  __syncthreads();
  if (t < 128){
    float s = 0.f, q = 0.f;
    for (int r = 0; r < 64; r++){ float v = z[r*128 + t]; s += v; q += v*v; }
    float mu = s*(1.f/64.f), var = q*(1.f/64.f) - mu*mu;
    float scv = g[t] * rsqrtf(var + BN_EPS);
    sc_s[t] = scv; sh_s[t] = b[t] - mu*scv;
  }
  __syncthreads();
  for (int i = t; i < 8192; i += 256){ int c = i & 127; z[i] = leaky(z[i]*sc_s[c] + sh_s[c]); }
  __syncthreads();
  for (int o = t; o < NGRAPH*OUTDIM; o += 256){
    int row = o/OUTDIM, c = o - row*OUTDIM;
    float acc = fc2b[c];
    for (int k = 0; k < 128; k++) acc += z[row*128 + k]*fc2w[k*OUTDIM + c];
    out[o] = acc;
  }
}

extern "C" void kernel_launch(void* const* d_in, const int* in_sizes, int n_in,
                              void* d_out, int out_size, void* d_ws, size_t ws_size,
                              hipStream_t stream){
  (void)in_sizes; (void)n_in; (void)out_size; (void)ws_size;
  const float* x     = (const float*)d_in[0];
  const int*   ei    = (const int*)d_in[1];
  const int*   batch = (const int*)d_in[2];
  const float* cwA[4]; const float* cbA[4]; const float* cwB[4]; const float* cbB[4];
  const float* bng[4]; const float* bnb[4];
  for (int l = 0; l < 4; l++){
    cwA[l] = (const float*)d_in[3 + l*6 + 0];
    cbA[l] = (const float*)d_in[3 + l*6 + 1];
    cwB[l] = (const float*)d_in[3 + l*6 + 2];
    cbB[l] = (const float*)d_in[3 + l*6 + 3];
    bng[l] = (const float*)d_in[3 + l*6 + 4];
    bnb[l] = (const float*)d_in[3 + l*6 + 5];
  }
  const float* fc1w = (const float*)d_in[27];
  const float* fc1b = (const float*)d_in[28];
  const float* fcg  = (const float*)d_in[29];
  const float* fcb  = (const float*)d_in[30];
  const float* fc2w = (const float*)d_in[31];
  const float* fc2b = (const float*)d_in[32];

  char* p = (char*)d_ws;
  auto alloc = [&](size_t bytes)->char* {
    char* r = p; p += (bytes + 511) & ~(size_t)511; return r;
  };
  int* deg     = (int*)alloc((size_t)N_NODES*4);
  int* offsets = (int*)alloc((size_t)(N_NODES+1)*4);
  int* cursor  = (int*)alloc((size_t)N_NODES*4);
  int* bsum    = (int*)alloc((size_t)SCAN_B*4);
  int* csr     = (int*)alloc((size_t)N_EDGES*4);
  unsigned short* Wfrag = (unsigned short*)alloc((size_t)8*32768*2);
  unsigned short* hbf   = (unsigned short*)alloc((size_t)PADN*128*2);
  unsigned* spB = (unsigned*)alloc((size_t)PADN*128*4);
  unsigned* spC = (unsigned*)alloc((size_t)PADN*128*4);
  float* stats  = (float*)alloc((size_t)(4*2048 + 8192 + 8192)*4);
  float* pooled = stats + 4*2048;
  float* z1     = pooled + 8192;

  hipMemsetAsync(deg, 0, (size_t)N_NODES*4, stream);
  hipMemsetAsync(stats, 0, (size_t)(4*2048 + 8192)*4, stream);

  convx_kernel<<<(N_NODES*32+255)/256, 256, 0, stream>>>(x, hbf);
  convw_kernel<<<8, 256, 0, stream>>>(cwA[0], cwB[0], cwA[1], cwB[1],
                                      cwA[2], cwB[2], cwA[3], cwB[3], Wfrag);
  hist_kernel<<<(N_EDGES+255)/256, 256, 0, stream>>>(ei + N_EDGES, deg);
  blocksum_kernel<<<SCAN_B, 256, 0, stream>>>(deg, bsum);
  scan2_kernel<<<SCAN_B, 256, 0, stream>>>(deg, bsum, offsets, cursor);
  fill_kernel<<<(N_EDGES+255)/256, 256, 0, stream>>>(ei, ei + N_EDGES, cursor, csr);

  for (int l = 0; l < 4; l++){
    if (l == 0)
      aggregate_kernel<false><<<12500, 256, 0, stream>>>((const unsigned*)hbf, offsets, csr,
            nullptr, nullptr, nullptr, (uint2*)spB);
    else
      aggregate_kernel<true><<<12500, 256, 0, stream>>>((const unsigned*)hbf, offsets, csr,
            stats + (l-1)*2048, bng[l-1], bnb[l-1], (uint2*)spB);
    gemm_kernel<false><<<NTILES, 256, 0, stream>>>(spB, Wfrag + (size_t)(2*l)*32768,
            cbA[l], spC, nullptr, nullptr);
    gemm_kernel<true><<<NTILES, 256, 0, stream>>>(spC, Wfrag + (size_t)(2*l+1)*32768,
            cbB[l], nullptr, hbf, stats + l*2048);
  }

  pool_kernel<<<NGRAPH*8, 128, 0, stream>>>(hbf, batch, stats + 3*2048, bng[3], bnb[3], pooled);
  fc1_kernel<<<NGRAPH, 128, 0, stream>>>(pooled, batch, fc1w, fc1b, z1);
  head2_kernel<<<1, 256, 0, stream>>>(z1, fcg, fcb, fc2w, fc2b, (float*)d_out);
}